// Round 4
// baseline (519.848 us; speedup 1.0000x reference)
//
#include <hip/hip_runtime.h>
#include <hip/hip_bf16.h>

// ODELSTMCell: B=16384, I=256, H=256, OH=64, 8 fixed dopri5 steps.
// prep_kernel : W_ih|W_hh -> bf16 [1024][512] in d_ws.
// lstm_kernel : MFMA GEMM via global_load_lds staging; M=64 blocks, grid(4,256).
// ode_kernel  : z-space dopri5 (no k buffers/registers):
//   arg_j = y + dt*(c_j*b2 + (sum_l a_jl z_l) @ W2^T), combos in 64-dim z-space.
//   Exchange mechanics identical to the verified R2 kernel (swizzled scalar
//   b16 LDS writes + contiguous short8 frag reads, canonical slot map).

#define B_N 16384
#define H_N 256

typedef __attribute__((ext_vector_type(8))) short short8;  // 8 x bf16
typedef __attribute__((ext_vector_type(4))) float f32x4;

__device__ __forceinline__ unsigned short f2bf_s(float x) {
  __hip_bfloat16 h = __float2bfloat16(x);
  return *reinterpret_cast<unsigned short*>(&h);
}

__device__ __forceinline__ short8 pack8f(const float* p) {
  const f32x4 a = *(const f32x4*)p;
  const f32x4 b = *(const f32x4*)(p + 4);
  short8 r;
  r[0] = (short)f2bf_s(a[0]); r[1] = (short)f2bf_s(a[1]);
  r[2] = (short)f2bf_s(a[2]); r[3] = (short)f2bf_s(a[3]);
  r[4] = (short)f2bf_s(b[0]); r[5] = (short)f2bf_s(b[1]);
  r[6] = (short)f2bf_s(b[2]); r[7] = (short)f2bf_s(b[3]);
  return r;
}

__device__ __forceinline__ float fast_sigmoid(float x) {
  return __builtin_amdgcn_rcpf(1.f + __expf(-x));
}
__device__ __forceinline__ float fast_tanh(float x) {
  x = fminf(15.f, fmaxf(-15.f, x));
  float e = __expf(2.f * x);
  return 1.f - 2.f * __builtin_amdgcn_rcpf(e + 1.f);
}

__device__ __forceinline__ void gl_lds16(const void* g, void* l) {
  __builtin_amdgcn_global_load_lds(
      (const __attribute__((address_space(1))) void*)g,
      (__attribute__((address_space(3))) void*)l, 16, 0, 0);
}

// ---------------------------------------------------------------------------
// prep: ws_B[1024][512] bf16; row n: k<256 from W_ih[n], k>=256 from W_hh[n].
// ---------------------------------------------------------------------------
__global__ __launch_bounds__(256) void prep_kernel(
    const float* __restrict__ Wih, const float* __restrict__ Whh,
    unsigned short* __restrict__ wsB) {
  int idx = blockIdx.x * 256 + threadIdx.x;
  int n = idx >> 6, c = idx & 63, k = c * 8;
  const float* src = (k < 256) ? (Wih + (size_t)n * 256 + k)
                               : (Whh + (size_t)n * 256 + (k - 256));
  *(short8*)(wsB + (size_t)n * 512 + k) = pack8f(src);
}

// ---------------------------------------------------------------------------
// lstm: grid (4, 256): blockIdx.x -> 64 h-units, blockIdx.y -> 64 samples
// (h fast in dispatch order so consecutive blocks share the A-slice in L2).
// 256 thr (4 waves); wave: 16 samples x (64 h x 4 gates).
// LDS: As f32 [64][64] (chunk-swizzled ^row&15), Bs bf16 [256][64] (^row&7).
// ---------------------------------------------------------------------------
__global__ __launch_bounds__(256, 3) void lstm_kernel(
    const float* __restrict__ x, const float* __restrict__ hp,
    const float* __restrict__ cp, const unsigned short* __restrict__ wsB,
    const float* __restrict__ bih, const float* __restrict__ bhh,
    float* __restrict__ out) {
  __shared__ __align__(16) float As[64 * 64];
  __shared__ __align__(16) unsigned short Bs[256 * 64];

  const int lane = threadIdx.x & 63;
  const int wv = threadIdx.x >> 6;
  const int s = lane & 15, q = lane >> 4;
  const int hb = blockIdx.x * 64;
  const int mb = blockIdx.y * 64;

  f32x4 acc[16];
#pragma unroll
  for (int tn = 0; tn < 16; ++tn) acc[tn] = (f32x4){0.f, 0.f, 0.f, 0.f};

  float bsum[16];
#pragma unroll
  for (int tn = 0; tn < 16; ++tn) {
    int n = (tn >> 2) * 256 + hb + (tn & 3) * 16 + s;
    bsum[tn] = bih[n] + bhh[n];
  }

  for (int kt8 = 0; kt8 < 8; ++kt8) {
    const int k0 = kt8 * 64;
    if (kt8) __syncthreads();  // WAR: previous compute done
    {
      const float* srcA = (k0 < 256) ? x : hp;
      const int kl = k0 & 255;
#pragma unroll
      for (int c = 0; c < 4; ++c) {
        int row = (wv * 4 + c) * 4 + (lane >> 4);
        int uc = (lane & 15) ^ (row & 15);
        gl_lds16(srcA + (size_t)(mb + row) * 256 + kl + uc * 4,
                 (char*)As + (wv * 4 + c) * 1024);
      }
    }
#pragma unroll
    for (int c = 0; c < 8; ++c) {
      int t = (wv * 8 + c) * 8 + (lane >> 3);
      int uc = (lane & 7) ^ (t & 7);
      int gr = (t >> 6) * 256 + hb + (t & 63);
      gl_lds16(wsB + (size_t)gr * 512 + k0 + uc * 8,
               (char*)Bs + (wv * 8 + c) * 1024);
    }
    __syncthreads();

#pragma unroll
    for (int kk = 0; kk < 2; ++kk) {
      int ar = wv * 16 + s;
      int c0 = kk * 8 + q * 2;
      float tmp[8];
      *(f32x4*)tmp = *(const f32x4*)((char*)As + ar * 256 + ((c0 ^ (ar & 15)) * 16));
      *(f32x4*)(tmp + 4) =
          *(const f32x4*)((char*)As + ar * 256 + (((c0 + 1) ^ (ar & 15)) * 16));
      short8 af = pack8f(tmp);
#pragma unroll
      for (int tn = 0; tn < 16; ++tn) {
        int t = (tn >> 2) * 64 + (tn & 3) * 16 + s;
        int ch = (kk * 4 + q) ^ (t & 7);
        short8 bf = *(const short8*)((char*)Bs + t * 128 + ch * 16);
        acc[tn] = __builtin_amdgcn_mfma_f32_16x16x32_bf16(af, bf, acc[tn], 0, 0, 0);
      }
    }
  }

  // fused epilogue
#pragma unroll
  for (int ntl = 0; ntl < 4; ++ntl)
#pragma unroll
    for (int r = 0; r < 4; ++r) {
      int sample = mb + wv * 16 + q * 4 + r;
      int h = hb + ntl * 16 + s;
      float gi = acc[ntl][r]      + bsum[ntl];
      float gf = acc[4 + ntl][r]  + bsum[4 + ntl];
      float gg = acc[8 + ntl][r]  + bsum[8 + ntl];
      float go = acc[12 + ntl][r] + bsum[12 + ntl];
      float iv = fast_sigmoid(gi), fv = fast_sigmoid(gf);
      float gv = fast_tanh(gg), ov = fast_sigmoid(go);
      float c = fv * cp[(size_t)sample * 256 + h] + iv * gv;
      float hv = ov * fast_tanh(c);
      out[(size_t)B_N * H_N + (size_t)sample * 256 + h] = c;
      out[(size_t)sample * 256 + h] = hv;
    }
}

// ---------------------------------------------------------------------------
// ode: z-space dopri5. 16 samples/block, 256 thr (4 waves).
// State y in regs (MFMA C/D layout); z1..z5 as f32x4 in regs.
// LDS: arg 8KB + z 2KB, R2-verified swizzled layouts. 12 barriers/step.
// ---------------------------------------------------------------------------
__global__ __launch_bounds__(256, 4) void ode_kernel(
    float* __restrict__ out, const float* __restrict__ ts,
    const float* __restrict__ W1, const float* __restrict__ b1,
    const float* __restrict__ W2, const float* __restrict__ b2) {
  __shared__ __align__(16) unsigned short argL[16 * 256];  // bf16, swizzled
  __shared__ __align__(16) unsigned short zL[16 * 64];     // bf16, swizzled
  char* argB = (char*)argL;
  char* zB = (char*)zL;

  const int tid = threadIdx.x;
  const int lane = tid & 63, wv = tid >> 6;
  const int s = lane & 15, q = lane >> 4;
  const int bb = blockIdx.x * 16;

  // weight fragments (persistent registers, canonical slot map)
  short8 w1f[8];
#pragma unroll
  for (int kt = 0; kt < 8; ++kt)
    w1f[kt] = pack8f(W1 + (size_t)(wv * 16 + s) * 256 + kt * 32 + q * 8);
  short8 w2f[4][2];
#pragma unroll
  for (int i = 0; i < 4; ++i)
#pragma unroll
    for (int kt = 0; kt < 2; ++kt)
      w2f[i][kt] = pack8f(W2 + (size_t)((wv * 4 + i) * 16 + s) * 64 + kt * 32 + q * 8);
  const float b1v = b1[wv * 16 + s];
  float b2v[4];
#pragma unroll
  for (int i = 0; i < 4; ++i) b2v[i] = b2[(wv * 4 + i) * 16 + s];

  const f32x4 dt4 = 0.125f * (*(const f32x4*)(ts + bb + q * 4));

  f32x4 yreg[4];
#pragma unroll
  for (int i = 0; i < 4; ++i)
#pragma unroll
    for (int r = 0; r < 4; ++r)
      yreg[i][r] = out[(size_t)(bb + q * 4 + r) * 256 + (wv * 4 + i) * 16 + s];

  const int n1 = wv * 16 + s;  // z-feature this thread produces

  auto mm1_tanh = [&]() -> f32x4 {
    f32x4 a = (f32x4){0.f, 0.f, 0.f, 0.f}, b = (f32x4){0.f, 0.f, 0.f, 0.f};
#pragma unroll
    for (int kt = 0; kt < 4; ++kt) {
      short8 fa = *(const short8*)(argB + s * 512 + (((kt * 4 + q) ^ (s & 7)) << 4));
      a = __builtin_amdgcn_mfma_f32_16x16x32_bf16(fa, w1f[kt], a, 0, 0, 0);
      short8 fb =
          *(const short8*)(argB + s * 512 + ((((kt + 4) * 4 + q) ^ (s & 7)) << 4));
      b = __builtin_amdgcn_mfma_f32_16x16x32_bf16(fb, w1f[kt + 4], b, 0, 0, 0);
    }
    f32x4 z;
#pragma unroll
    for (int r = 0; r < 4; ++r) z[r] = fast_tanh(a[r] + b[r] + b1v);
    return z;
  };

  auto store_zc = [&](f32x4 zc) {
#pragma unroll
    for (int r = 0; r < 4; ++r) {
      int m = q * 4 + r;
      *(unsigned short*)(zB + m * 128 +
                         ((((n1 >> 3) ^ (m & 7)) << 4) + (n1 & 7) * 2)) =
          f2bf_s(zc[r]);
    }
  };

  auto mm2o = [&](f32x4 (&o)[4]) {
    short8 za0 = *(const short8*)(zB + s * 128 + ((q ^ (s & 7)) << 4));
    short8 za1 = *(const short8*)(zB + s * 128 + (((4 + q) ^ (s & 7)) << 4));
#pragma unroll
    for (int i = 0; i < 4; ++i) {
      f32x4 t = (f32x4){0.f, 0.f, 0.f, 0.f};
      t = __builtin_amdgcn_mfma_f32_16x16x32_bf16(za0, w2f[i][0], t, 0, 0, 0);
      t = __builtin_amdgcn_mfma_f32_16x16x32_bf16(za1, w2f[i][1], t, 0, 0, 0);
      o[i] = t;
    }
  };

  auto store_arg = [&](const f32x4 (&v)[4]) {
#pragma unroll
    for (int i = 0; i < 4; ++i)
#pragma unroll
      for (int r = 0; r < 4; ++r) {
        int m = q * 4 + r;
        int n = (wv * 4 + i) * 16 + s;
        *(unsigned short*)(argB + m * 512 +
                           ((((n >> 3) ^ (m & 7)) << 4) + (n & 7) * 2)) =
            f2bf_s(v[i][r]);
      }
  };

  auto arg_stage = [&](float sj) {
    f32x4 o[4];
    mm2o(o);
    f32x4 av[4];
#pragma unroll
    for (int i = 0; i < 4; ++i)
#pragma unroll
      for (int r = 0; r < 4; ++r)
        av[i][r] = fmaf(dt4[r], fmaf(sj, b2v[i], o[i][r]), yreg[i][r]);
    store_arg(av);
  };

  const float A31 = 3.f / 40.f, A32 = 9.f / 40.f;
  const float A41 = 44.f / 45.f, A42 = -56.f / 15.f, A43 = 32.f / 9.f;
  const float A51 = 19372.f / 6561.f, A52 = -25360.f / 2187.f,
              A53 = 64448.f / 6561.f, A54 = -212.f / 729.f;
  const float A61 = 9017.f / 3168.f, A62 = -355.f / 33.f, A63 = 46732.f / 5247.f,
              A64 = 49.f / 176.f, A65 = -5103.f / 18656.f;
  const float C1 = 35.f / 384.f, C3 = 500.f / 1113.f, C4 = 125.f / 192.f,
              C5 = -2187.f / 6784.f, C6 = 11.f / 84.f;

  for (int st = 0; st < 8; ++st) {
    store_arg(yreg);  // arg1 = y (argB free: all reads drained at last barrier)
    __syncthreads();
    f32x4 z1 = mm1_tanh();
    store_zc(0.2f * z1);
    __syncthreads();
    arg_stage(0.2f);  // arg2
    __syncthreads();
    f32x4 z2 = mm1_tanh();
    store_zc(A31 * z1 + A32 * z2);
    __syncthreads();
    arg_stage(0.3f);  // arg3
    __syncthreads();
    f32x4 z3 = mm1_tanh();
    store_zc(A41 * z1 + A42 * z2 + A43 * z3);
    __syncthreads();
    arg_stage(0.8f);  // arg4
    __syncthreads();
    f32x4 z4 = mm1_tanh();
    store_zc(A51 * z1 + A52 * z2 + A53 * z3 + A54 * z4);
    __syncthreads();
    arg_stage(8.f / 9.f);  // arg5
    __syncthreads();
    f32x4 z5 = mm1_tanh();
    store_zc(A61 * z1 + A62 * z2 + A63 * z3 + A64 * z4 + A65 * z5);
    __syncthreads();
    arg_stage(1.0f);  // arg6
    __syncthreads();
    f32x4 z6 = mm1_tanh();
    store_zc(C1 * z1 + C3 * z3 + C4 * z4 + C5 * z5 + C6 * z6);
    __syncthreads();
    {  // y += dt*(b2 + zC @ W2^T)
      f32x4 o[4];
      mm2o(o);
#pragma unroll
      for (int i = 0; i < 4; ++i)
#pragma unroll
        for (int r = 0; r < 4; ++r)
          yreg[i][r] = fmaf(dt4[r], b2v[i] + o[i][r], yreg[i][r]);
    }
  }

  // store h_ode
#pragma unroll
  for (int i = 0; i < 4; ++i)
#pragma unroll
    for (int r = 0; r < 4; ++r)
      out[(size_t)(bb + q * 4 + r) * 256 + (wv * 4 + i) * 16 + s] = yreg[i][r];
}

extern "C" void kernel_launch(void* const* d_in, const int* in_sizes, int n_in,
                              void* d_out, int out_size, void* d_ws, size_t ws_size,
                              hipStream_t stream) {
  const float* x   = (const float*)d_in[0];
  const float* hp  = (const float*)d_in[1];
  const float* cp  = (const float*)d_in[2];
  const float* ts  = (const float*)d_in[3];
  const float* Wih = (const float*)d_in[4];
  const float* Whh = (const float*)d_in[5];
  const float* bih = (const float*)d_in[6];
  const float* bhh = (const float*)d_in[7];
  const float* W1  = (const float*)d_in[8];
  const float* b1  = (const float*)d_in[9];
  const float* W2  = (const float*)d_in[10];
  const float* b2  = (const float*)d_in[11];
  float* out = (float*)d_out;
  unsigned short* wsB = (unsigned short*)d_ws;  // 1 MB bf16 weights

  prep_kernel<<<256, 256, 0, stream>>>(Wih, Whh, wsB);
  lstm_kernel<<<dim3(4, 256), 256, 0, stream>>>(x, hp, cp, wsB, bih, bhh, out);
  ode_kernel<<<1024, 256, 0, stream>>>(out, ts, W1, b1, W2, b2);
}

// Round 5
// 129.745 us; speedup vs baseline: 4.0067x; 4.0067x over previous
//
#include <hip/hip_runtime.h>
#include <hip/hip_bf16.h>

// ODELSTMCell: B=16384, I=256, H=256, OH=64, 8 fixed dopri5 steps.
// prep_kernel : W_ih|W_hh -> bf16 [1024][512] in d_ws.
// lstm_kernel : MFMA GEMM via global_load_lds staging (R2/R4-verified).
// ode_kernel  : TRANSPOSED z-space dopri5. 32 samples/block, 4 waves,
//   launch_bounds(256,2) (R4 lesson: (256,4) spilled weights -> 1.4GB scratch).
//   MFMA: A = weights (frag data identical to R2-verified), B = state with
//   samples as the N dim -> thread owns 4 consecutive features of 1 sample:
//   b64 LDS writes, f32x4 global I/O, conflict-free chunk-XOR swizzle.

#define B_N 16384
#define H_N 256

typedef __attribute__((ext_vector_type(8))) short short8;          // 8 x bf16
typedef __attribute__((ext_vector_type(4))) unsigned short u16x4;  // 4 x bf16
typedef __attribute__((ext_vector_type(4))) float f32x4;

__device__ __forceinline__ unsigned short f2bf_s(float x) {
  __hip_bfloat16 h = __float2bfloat16(x);
  return *reinterpret_cast<unsigned short*>(&h);
}

__device__ __forceinline__ short8 pack8f(const float* p) {
  const f32x4 a = *(const f32x4*)p;
  const f32x4 b = *(const f32x4*)(p + 4);
  short8 r;
  r[0] = (short)f2bf_s(a[0]); r[1] = (short)f2bf_s(a[1]);
  r[2] = (short)f2bf_s(a[2]); r[3] = (short)f2bf_s(a[3]);
  r[4] = (short)f2bf_s(b[0]); r[5] = (short)f2bf_s(b[1]);
  r[6] = (short)f2bf_s(b[2]); r[7] = (short)f2bf_s(b[3]);
  return r;
}

__device__ __forceinline__ u16x4 pack4(f32x4 v) {
  u16x4 r;
  r[0] = f2bf_s(v[0]); r[1] = f2bf_s(v[1]);
  r[2] = f2bf_s(v[2]); r[3] = f2bf_s(v[3]);
  return r;
}

__device__ __forceinline__ float fast_sigmoid(float x) {
  return __builtin_amdgcn_rcpf(1.f + __expf(-x));
}
__device__ __forceinline__ float fast_tanh(float x) {
  x = fminf(15.f, fmaxf(-15.f, x));
  float e = __expf(2.f * x);
  return 1.f - 2.f * __builtin_amdgcn_rcpf(e + 1.f);
}

__device__ __forceinline__ void gl_lds16(const void* g, void* l) {
  __builtin_amdgcn_global_load_lds(
      (const __attribute__((address_space(1))) void*)g,
      (__attribute__((address_space(3))) void*)l, 16, 0, 0);
}

// ---------------------------------------------------------------------------
// prep: ws_B[1024][512] bf16; row n: k<256 from W_ih[n], k>=256 from W_hh[n].
// ---------------------------------------------------------------------------
__global__ __launch_bounds__(256) void prep_kernel(
    const float* __restrict__ Wih, const float* __restrict__ Whh,
    unsigned short* __restrict__ wsB) {
  int idx = blockIdx.x * 256 + threadIdx.x;
  int n = idx >> 6, c = idx & 63, k = c * 8;
  const float* src = (k < 256) ? (Wih + (size_t)n * 256 + k)
                               : (Whh + (size_t)n * 256 + (k - 256));
  *(short8*)(wsB + (size_t)n * 512 + k) = pack8f(src);
}

// ---------------------------------------------------------------------------
// lstm: grid (4, 256), 256 thr (unchanged from R4 — passed, ~30µs).
// ---------------------------------------------------------------------------
__global__ __launch_bounds__(256, 3) void lstm_kernel(
    const float* __restrict__ x, const float* __restrict__ hp,
    const float* __restrict__ cp, const unsigned short* __restrict__ wsB,
    const float* __restrict__ bih, const float* __restrict__ bhh,
    float* __restrict__ out) {
  __shared__ __align__(16) float As[64 * 64];
  __shared__ __align__(16) unsigned short Bs[256 * 64];

  const int lane = threadIdx.x & 63;
  const int wv = threadIdx.x >> 6;
  const int s = lane & 15, q = lane >> 4;
  const int hb = blockIdx.x * 64;
  const int mb = blockIdx.y * 64;

  f32x4 acc[16];
#pragma unroll
  for (int tn = 0; tn < 16; ++tn) acc[tn] = (f32x4){0.f, 0.f, 0.f, 0.f};

  float bsum[16];
#pragma unroll
  for (int tn = 0; tn < 16; ++tn) {
    int n = (tn >> 2) * 256 + hb + (tn & 3) * 16 + s;
    bsum[tn] = bih[n] + bhh[n];
  }

  for (int kt8 = 0; kt8 < 8; ++kt8) {
    const int k0 = kt8 * 64;
    if (kt8) __syncthreads();
    {
      const float* srcA = (k0 < 256) ? x : hp;
      const int kl = k0 & 255;
#pragma unroll
      for (int c = 0; c < 4; ++c) {
        int row = (wv * 4 + c) * 4 + (lane >> 4);
        int uc = (lane & 15) ^ (row & 15);
        gl_lds16(srcA + (size_t)(mb + row) * 256 + kl + uc * 4,
                 (char*)As + (wv * 4 + c) * 1024);
      }
    }
#pragma unroll
    for (int c = 0; c < 8; ++c) {
      int t = (wv * 8 + c) * 8 + (lane >> 3);
      int uc = (lane & 7) ^ (t & 7);
      int gr = (t >> 6) * 256 + hb + (t & 63);
      gl_lds16(wsB + (size_t)gr * 512 + k0 + uc * 8,
               (char*)Bs + (wv * 8 + c) * 1024);
    }
    __syncthreads();

#pragma unroll
    for (int kk = 0; kk < 2; ++kk) {
      int ar = wv * 16 + s;
      int c0 = kk * 8 + q * 2;
      float tmp[8];
      *(f32x4*)tmp = *(const f32x4*)((char*)As + ar * 256 + ((c0 ^ (ar & 15)) * 16));
      *(f32x4*)(tmp + 4) =
          *(const f32x4*)((char*)As + ar * 256 + (((c0 + 1) ^ (ar & 15)) * 16));
      short8 af = pack8f(tmp);
#pragma unroll
      for (int tn = 0; tn < 16; ++tn) {
        int t = (tn >> 2) * 64 + (tn & 3) * 16 + s;
        int ch = (kk * 4 + q) ^ (t & 7);
        short8 bf = *(const short8*)((char*)Bs + t * 128 + ch * 16);
        acc[tn] = __builtin_amdgcn_mfma_f32_16x16x32_bf16(af, bf, acc[tn], 0, 0, 0);
      }
    }
  }

#pragma unroll
  for (int ntl = 0; ntl < 4; ++ntl)
#pragma unroll
    for (int r = 0; r < 4; ++r) {
      int sample = mb + wv * 16 + q * 4 + r;
      int h = hb + ntl * 16 + s;
      float gi = acc[ntl][r]      + bsum[ntl];
      float gf = acc[4 + ntl][r]  + bsum[4 + ntl];
      float gg = acc[8 + ntl][r]  + bsum[8 + ntl];
      float go = acc[12 + ntl][r] + bsum[12 + ntl];
      float iv = fast_sigmoid(gi), fv = fast_sigmoid(gf);
      float gv = fast_tanh(gg), ov = fast_sigmoid(go);
      float c = fv * cp[(size_t)sample * 256 + h] + iv * gv;
      float hv = ov * fast_tanh(c);
      out[(size_t)B_N * H_N + (size_t)sample * 256 + h] = c;
      out[(size_t)sample * 256 + h] = hv;
    }
}

// ---------------------------------------------------------------------------
// ode: transposed z-space dopri5. 32 samples/block (2 N-tiles), 256 thr.
// Thread (s,q) of wave wv owns features wv*64+i*16+q*4..+3 of sample t*16+s.
// MFMA: A = weight frags (R2-verified data), B = state frags from LDS.
// LDS: argT[32][256] bf16 16KB, zcT[32][64] bf16 4KB; 16B-chunk XOR swizzle
//   (chunk ^ (s&7)) — derived conflict-free for both b64 writes & b128 reads.
// ---------------------------------------------------------------------------
__global__ __launch_bounds__(256, 2) void ode_kernel(
    float* __restrict__ out, const float* __restrict__ ts,
    const float* __restrict__ W1, const float* __restrict__ b1,
    const float* __restrict__ W2, const float* __restrict__ b2) {
  __shared__ __align__(16) unsigned short argT[32 * 256];
  __shared__ __align__(16) unsigned short zcT[32 * 64];
  char* argB = (char*)argT;
  char* zB = (char*)zcT;

  const int tid = threadIdx.x;
  const int lane = tid & 63, wv = tid >> 6;
  const int s = lane & 15, q = lane >> 4;
  const int bb = blockIdx.x * 32;
  const int sx7 = s & 7;

  // --- weight A-frags: identical data layout to R2-verified fragments ---
  short8 w1f[8];
#pragma unroll
  for (int kt = 0; kt < 8; ++kt)
    w1f[kt] = pack8f(W1 + (size_t)(wv * 16 + s) * 256 + kt * 32 + q * 8);
  short8 w2f[4][2];
#pragma unroll
  for (int i = 0; i < 4; ++i)
#pragma unroll
    for (int kt = 0; kt < 2; ++kt)
      w2f[i][kt] = pack8f(W2 + (size_t)(wv * 64 + i * 16 + s) * 64 + kt * 32 + q * 8);

  // biases as feature-vectors (r-indexed)
  const f32x4 b1v = *(const f32x4*)(b1 + wv * 16 + q * 4);
  f32x4 b2v[4];
#pragma unroll
  for (int i = 0; i < 4; ++i) b2v[i] = *(const f32x4*)(b2 + wv * 64 + i * 16 + q * 4);

  float dt[2];
#pragma unroll
  for (int t = 0; t < 2; ++t) dt[t] = ts[bb + t * 16 + s] * 0.125f;

  // y0 (lstm wrote h to out[0:BH) in [sample][feature])
  f32x4 yreg[2][4];
#pragma unroll
  for (int t = 0; t < 2; ++t)
#pragma unroll
    for (int i = 0; i < 4; ++i)
      yreg[t][i] = *(const f32x4*)(out + (size_t)(bb + t * 16 + s) * 256 +
                                   wv * 64 + i * 16 + q * 4);

  f32x4 z1[2], z2[2], z3[2], z4[2], z5[2], z6[2];

  // LDS address pieces
  const int aw0 = ((wv * 8 + (q >> 1)) ^ sx7);  // arg write chunk base (i=0); +2 per i
  const int woff = (q & 1) * 8;
  const int zw = (((wv * 2 + (q >> 1)) ^ sx7) << 4) + woff;

  auto store_arg = [&](const f32x4 (&v)[2][4]) {
#pragma unroll
    for (int t = 0; t < 2; ++t) {
      char* rp = argB + (t * 16 + s) * 512;
#pragma unroll
      for (int i = 0; i < 4; ++i)
        *(u16x4*)(rp + ((((wv * 8 + i * 2 + (q >> 1)) ^ sx7) << 4) + woff)) =
            pack4(v[t][i]);
    }
  };

  auto mm1_tanh = [&](f32x4 (&z)[2]) {
#pragma unroll
    for (int t = 0; t < 2; ++t) {
      const char* rp = argB + (t * 16 + s) * 512;
      f32x4 a = (f32x4){0.f, 0.f, 0.f, 0.f}, b = (f32x4){0.f, 0.f, 0.f, 0.f};
#pragma unroll
      for (int kt = 0; kt < 4; ++kt) {
        short8 fa = *(const short8*)(rp + (((kt * 4 + q) ^ sx7) << 4));
        a = __builtin_amdgcn_mfma_f32_16x16x32_bf16(w1f[kt], fa, a, 0, 0, 0);
        short8 fb = *(const short8*)(rp + ((((kt + 4) * 4 + q) ^ sx7) << 4));
        b = __builtin_amdgcn_mfma_f32_16x16x32_bf16(w1f[kt + 4], fb, b, 0, 0, 0);
      }
#pragma unroll
      for (int r = 0; r < 4; ++r) z[t][r] = fast_tanh(a[r] + b[r] + b1v[r]);
    }
  };

  auto store_zc = [&](const f32x4 (&zc)[2]) {
#pragma unroll
    for (int t = 0; t < 2; ++t)
      *(u16x4*)(zB + (t * 16 + s) * 128 + zw) = pack4(zc[t]);
  };

  auto mm2o = [&](f32x4 (&o)[2][4]) {
#pragma unroll
    for (int t = 0; t < 2; ++t) {
      const char* rp = zB + (t * 16 + s) * 128;
      short8 zf0 = *(const short8*)(rp + ((q ^ sx7) << 4));
      short8 zf1 = *(const short8*)(rp + (((4 + q) ^ sx7) << 4));
#pragma unroll
      for (int i = 0; i < 4; ++i) {
        f32x4 tt = (f32x4){0.f, 0.f, 0.f, 0.f};
        tt = __builtin_amdgcn_mfma_f32_16x16x32_bf16(w2f[i][0], zf0, tt, 0, 0, 0);
        tt = __builtin_amdgcn_mfma_f32_16x16x32_bf16(w2f[i][1], zf1, tt, 0, 0, 0);
        o[t][i] = tt;
      }
    }
  };

  auto arg_stage = [&](float sj) {
    f32x4 o[2][4];
    mm2o(o);
    f32x4 av[2][4];
#pragma unroll
    for (int t = 0; t < 2; ++t)
#pragma unroll
      for (int i = 0; i < 4; ++i)
#pragma unroll
        for (int r = 0; r < 4; ++r)
          av[t][i][r] = fmaf(dt[t], fmaf(sj, b2v[i][r], o[t][i][r]), yreg[t][i][r]);
    store_arg(av);
  };

  const float A31 = 3.f / 40.f, A32 = 9.f / 40.f;
  const float A41 = 44.f / 45.f, A42 = -56.f / 15.f, A43 = 32.f / 9.f;
  const float A51 = 19372.f / 6561.f, A52 = -25360.f / 2187.f,
              A53 = 64448.f / 6561.f, A54 = -212.f / 729.f;
  const float A61 = 9017.f / 3168.f, A62 = -355.f / 33.f, A63 = 46732.f / 5247.f,
              A64 = 49.f / 176.f, A65 = -5103.f / 18656.f;
  const float C1 = 35.f / 384.f, C3 = 500.f / 1113.f, C4 = 125.f / 192.f,
              C5 = -2187.f / 6784.f, C6 = 11.f / 84.f;

  for (int st = 0; st < 8; ++st) {
    store_arg(yreg);  // arg1 = y
    __syncthreads();
    mm1_tanh(z1);
    {
      f32x4 zc[2];
#pragma unroll
      for (int t = 0; t < 2; ++t) zc[t] = 0.2f * z1[t];
      store_zc(zc);
    }
    __syncthreads();
    arg_stage(0.2f);
    __syncthreads();
    mm1_tanh(z2);
    {
      f32x4 zc[2];
#pragma unroll
      for (int t = 0; t < 2; ++t) zc[t] = A31 * z1[t] + A32 * z2[t];
      store_zc(zc);
    }
    __syncthreads();
    arg_stage(0.3f);
    __syncthreads();
    mm1_tanh(z3);
    {
      f32x4 zc[2];
#pragma unroll
      for (int t = 0; t < 2; ++t) zc[t] = A41 * z1[t] + A42 * z2[t] + A43 * z3[t];
      store_zc(zc);
    }
    __syncthreads();
    arg_stage(0.8f);
    __syncthreads();
    mm1_tanh(z4);
    {
      f32x4 zc[2];
#pragma unroll
      for (int t = 0; t < 2; ++t)
        zc[t] = A51 * z1[t] + A52 * z2[t] + A53 * z3[t] + A54 * z4[t];
      store_zc(zc);
    }
    __syncthreads();
    arg_stage(8.f / 9.f);
    __syncthreads();
    mm1_tanh(z5);
    {
      f32x4 zc[2];
#pragma unroll
      for (int t = 0; t < 2; ++t)
        zc[t] = A61 * z1[t] + A62 * z2[t] + A63 * z3[t] + A64 * z4[t] + A65 * z5[t];
      store_zc(zc);
    }
    __syncthreads();
    arg_stage(1.0f);
    __syncthreads();
    mm1_tanh(z6);
    {
      f32x4 zc[2];
#pragma unroll
      for (int t = 0; t < 2; ++t)
        zc[t] = C1 * z1[t] + C3 * z3[t] + C4 * z4[t] + C5 * z5[t] + C6 * z6[t];
      store_zc(zc);
    }
    __syncthreads();
    {  // y += dt*(b2 + zC @ W2^T)
      f32x4 o[2][4];
      mm2o(o);
#pragma unroll
      for (int t = 0; t < 2; ++t)
#pragma unroll
        for (int i = 0; i < 4; ++i)
#pragma unroll
          for (int r = 0; r < 4; ++r)
            yreg[t][i][r] = fmaf(dt[t], b2v[i][r] + o[t][i][r], yreg[t][i][r]);
    }
    __syncthreads();  // zcT reads drained before next step's overwrite
  }

  // store h_ode (f32x4 per (t,i))
#pragma unroll
  for (int t = 0; t < 2; ++t)
#pragma unroll
    for (int i = 0; i < 4; ++i)
      *(f32x4*)(out + (size_t)(bb + t * 16 + s) * 256 + wv * 64 + i * 16 + q * 4) =
          yreg[t][i];
}

extern "C" void kernel_launch(void* const* d_in, const int* in_sizes, int n_in,
                              void* d_out, int out_size, void* d_ws, size_t ws_size,
                              hipStream_t stream) {
  const float* x   = (const float*)d_in[0];
  const float* hp  = (const float*)d_in[1];
  const float* cp  = (const float*)d_in[2];
  const float* ts  = (const float*)d_in[3];
  const float* Wih = (const float*)d_in[4];
  const float* Whh = (const float*)d_in[5];
  const float* bih = (const float*)d_in[6];
  const float* bhh = (const float*)d_in[7];
  const float* W1  = (const float*)d_in[8];
  const float* b1  = (const float*)d_in[9];
  const float* W2  = (const float*)d_in[10];
  const float* b2  = (const float*)d_in[11];
  float* out = (float*)d_out;
  unsigned short* wsB = (unsigned short*)d_ws;  // 1 MB bf16 weights

  prep_kernel<<<256, 256, 0, stream>>>(Wih, Whh, wsB);
  lstm_kernel<<<dim3(4, 256), 256, 0, stream>>>(x, hp, cp, wsB, bih, bhh, out);
  ode_kernel<<<512, 256, 0, stream>>>(out, ts, W1, b1, W2, b2);
}

// Round 6
// 97.673 us; speedup vs baseline: 5.3223x; 1.3284x over previous
//
#include <hip/hip_runtime.h>
#include <hip/hip_bf16.h>

// ODELSTMCell: B=16384, I=256, H=256, OH=64, 8 fixed dopri5 steps.
// prep_kernel : wsB = [W_ih|W_hh] bf16 [1024][512]; Wc = W1@W2 (64x64 bf16);
//               u = b2@W1^T (64 f32).
// lstm_kernel : MFMA GEMM via global_load_lds staging (R2/R4/R5-verified).
// ode_kernel  : operator-composite dopri5 in G-space (G = y@W1^T, 64-dim):
//   z_j = tanh(G + dt*(c_j*u + zc_j@Wc^T) + b1);  G += dt*(u + zC@Wc^T);
//   y_out = y0 + 8*dt*b2 + dt*(sum zC)@W2^T.
//   mm1 once (G0), mm2 once (epilogue); loop uses only 64x64 Wc matmuls.
//   LDS: two 4KB zcT buffers (double-buffered -> no WAR barriers).

#define B_N 16384
#define H_N 256

typedef __attribute__((ext_vector_type(8))) short short8;          // 8 x bf16
typedef __attribute__((ext_vector_type(4))) unsigned short u16x4;  // 4 x bf16
typedef __attribute__((ext_vector_type(4))) float f32x4;

__device__ __forceinline__ unsigned short f2bf_s(float x) {
  __hip_bfloat16 h = __float2bfloat16(x);
  return *reinterpret_cast<unsigned short*>(&h);
}

__device__ __forceinline__ short8 pack8f(const float* p) {
  const f32x4 a = *(const f32x4*)p;
  const f32x4 b = *(const f32x4*)(p + 4);
  short8 r;
  r[0] = (short)f2bf_s(a[0]); r[1] = (short)f2bf_s(a[1]);
  r[2] = (short)f2bf_s(a[2]); r[3] = (short)f2bf_s(a[3]);
  r[4] = (short)f2bf_s(b[0]); r[5] = (short)f2bf_s(b[1]);
  r[6] = (short)f2bf_s(b[2]); r[7] = (short)f2bf_s(b[3]);
  return r;
}

__device__ __forceinline__ u16x4 pack4(f32x4 v) {
  u16x4 r;
  r[0] = f2bf_s(v[0]); r[1] = f2bf_s(v[1]);
  r[2] = f2bf_s(v[2]); r[3] = f2bf_s(v[3]);
  return r;
}

__device__ __forceinline__ float fast_sigmoid(float x) {
  return __builtin_amdgcn_rcpf(1.f + __expf(-x));
}
__device__ __forceinline__ float fast_tanh(float x) {
  x = fminf(15.f, fmaxf(-15.f, x));
  float e = __expf(2.f * x);
  return 1.f - 2.f * __builtin_amdgcn_rcpf(e + 1.f);
}

__device__ __forceinline__ void gl_lds16(const void* g, void* l) {
  __builtin_amdgcn_global_load_lds(
      (const __attribute__((address_space(1))) void*)g,
      (__attribute__((address_space(3))) void*)l, 16, 0, 0);
}

// ---------------------------------------------------------------------------
// prep: blocks [0,256): wsB rows; [256,272): Wc = W1@W2; 272: u = b2@W1^T.
// ---------------------------------------------------------------------------
__global__ __launch_bounds__(256) void prep_kernel(
    const float* __restrict__ Wih, const float* __restrict__ Whh,
    const float* __restrict__ W1, const float* __restrict__ W2,
    const float* __restrict__ b2,
    unsigned short* __restrict__ wsB, unsigned short* __restrict__ wcB,
    float* __restrict__ uF) {
  const int bx = blockIdx.x;
  if (bx < 256) {
    int idx = bx * 256 + threadIdx.x;
    int n = idx >> 6, c = idx & 63, k = c * 8;
    const float* src = (k < 256) ? (Wih + (size_t)n * 256 + k)
                                 : (Whh + (size_t)n * 256 + (k - 256));
    *(short8*)(wsB + (size_t)n * 512 + k) = pack8f(src);
  } else if (bx < 272) {
    int idx = (bx - 256) * 256 + threadIdx.x;  // [0,4096)
    int f = idx >> 6, o = idx & 63;
    float acc = 0.f;
    for (int h = 0; h < 256; ++h)
      acc = fmaf(W1[f * 256 + h], W2[h * 64 + o], acc);
    wcB[f * 64 + o] = f2bf_s(acc);
  } else {
    int f = threadIdx.x;
    if (f < 64) {
      float acc = 0.f;
      for (int h = 0; h < 256; ++h) acc = fmaf(W1[f * 256 + h], b2[h], acc);
      uF[f] = acc;
    }
  }
}

// ---------------------------------------------------------------------------
// lstm: grid (4, 256), 256 thr (verified; untouched).
// ---------------------------------------------------------------------------
__global__ __launch_bounds__(256, 3) void lstm_kernel(
    const float* __restrict__ x, const float* __restrict__ hp,
    const float* __restrict__ cp, const unsigned short* __restrict__ wsB,
    const float* __restrict__ bih, const float* __restrict__ bhh,
    float* __restrict__ out) {
  __shared__ __align__(16) float As[64 * 64];
  __shared__ __align__(16) unsigned short Bs[256 * 64];

  const int lane = threadIdx.x & 63;
  const int wv = threadIdx.x >> 6;
  const int s = lane & 15, q = lane >> 4;
  const int hb = blockIdx.x * 64;
  const int mb = blockIdx.y * 64;

  f32x4 acc[16];
#pragma unroll
  for (int tn = 0; tn < 16; ++tn) acc[tn] = (f32x4){0.f, 0.f, 0.f, 0.f};

  float bsum[16];
#pragma unroll
  for (int tn = 0; tn < 16; ++tn) {
    int n = (tn >> 2) * 256 + hb + (tn & 3) * 16 + s;
    bsum[tn] = bih[n] + bhh[n];
  }

  for (int kt8 = 0; kt8 < 8; ++kt8) {
    const int k0 = kt8 * 64;
    if (kt8) __syncthreads();
    {
      const float* srcA = (k0 < 256) ? x : hp;
      const int kl = k0 & 255;
#pragma unroll
      for (int c = 0; c < 4; ++c) {
        int row = (wv * 4 + c) * 4 + (lane >> 4);
        int uc = (lane & 15) ^ (row & 15);
        gl_lds16(srcA + (size_t)(mb + row) * 256 + kl + uc * 4,
                 (char*)As + (wv * 4 + c) * 1024);
      }
    }
#pragma unroll
    for (int c = 0; c < 8; ++c) {
      int t = (wv * 8 + c) * 8 + (lane >> 3);
      int uc = (lane & 7) ^ (t & 7);
      int gr = (t >> 6) * 256 + hb + (t & 63);
      gl_lds16(wsB + (size_t)gr * 512 + k0 + uc * 8,
               (char*)Bs + (wv * 8 + c) * 1024);
    }
    __syncthreads();

#pragma unroll
    for (int kk = 0; kk < 2; ++kk) {
      int ar = wv * 16 + s;
      int c0 = kk * 8 + q * 2;
      float tmp[8];
      *(f32x4*)tmp = *(const f32x4*)((char*)As + ar * 256 + ((c0 ^ (ar & 15)) * 16));
      *(f32x4*)(tmp + 4) =
          *(const f32x4*)((char*)As + ar * 256 + (((c0 + 1) ^ (ar & 15)) * 16));
      short8 af = pack8f(tmp);
#pragma unroll
      for (int tn = 0; tn < 16; ++tn) {
        int t = (tn >> 2) * 64 + (tn & 3) * 16 + s;
        int ch = (kk * 4 + q) ^ (t & 7);
        short8 bf = *(const short8*)((char*)Bs + t * 128 + ch * 16);
        acc[tn] = __builtin_amdgcn_mfma_f32_16x16x32_bf16(af, bf, acc[tn], 0, 0, 0);
      }
    }
  }

#pragma unroll
  for (int ntl = 0; ntl < 4; ++ntl)
#pragma unroll
    for (int r = 0; r < 4; ++r) {
      int sample = mb + wv * 16 + q * 4 + r;
      int h = hb + ntl * 16 + s;
      float gi = acc[ntl][r]      + bsum[ntl];
      float gf = acc[4 + ntl][r]  + bsum[4 + ntl];
      float gg = acc[8 + ntl][r]  + bsum[8 + ntl];
      float go = acc[12 + ntl][r] + bsum[12 + ntl];
      float iv = fast_sigmoid(gi), fv = fast_sigmoid(gf);
      float gv = fast_tanh(gg), ov = fast_sigmoid(go);
      float c = fv * cp[(size_t)sample * 256 + h] + iv * gv;
      float hv = ov * fast_tanh(c);
      out[(size_t)B_N * H_N + (size_t)sample * 256 + h] = c;
      out[(size_t)sample * 256 + h] = hv;
    }
}

// ---------------------------------------------------------------------------
// ode: G-space dopri5. 32 samples/block (t=0,1), 256 thr, 4 waves.
// Thread (s,q,wv): G/z/SC hold features wv*16+q*4..+3 of sample t*16+s;
// yreg holds features wv*64+i*16+q*4..+3. zcT exchange = R5-verified layout.
// ---------------------------------------------------------------------------
__global__ __launch_bounds__(256, 2) void ode_kernel(
    float* __restrict__ out, const float* __restrict__ ts,
    const float* __restrict__ W1, const unsigned short* __restrict__ wcB,
    const float* __restrict__ uF, const float* __restrict__ W2,
    const float* __restrict__ b1, const float* __restrict__ b2) {
  __shared__ __align__(16) unsigned short zcA[32 * 64];
  __shared__ __align__(16) unsigned short zcB2[32 * 64];
  char* zA = (char*)zcA;
  char* zB = (char*)zcB2;

  const int tid = threadIdx.x;
  const int lane = tid & 63, wv = tid >> 6;
  const int s = lane & 15, q = lane >> 4;
  const int bb = blockIdx.x * 32;
  const int sx7 = s & 7;

  // Wc A-frags (already bf16): row wv*16+s, k = kt*32 + q*8
  short8 wcf[2];
#pragma unroll
  for (int kt = 0; kt < 2; ++kt)
    wcf[kt] = *(const short8*)(wcB + (size_t)(wv * 16 + s) * 64 + kt * 32 + q * 8);

  const f32x4 b1v = *(const f32x4*)(b1 + wv * 16 + q * 4);
  const f32x4 u4 = *(const f32x4*)(uF + wv * 16 + q * 4);

  float dt[2];
#pragma unroll
  for (int t = 0; t < 2; ++t) dt[t] = ts[bb + t * 16 + s] * 0.125f;

  // y0 (for final update)
  f32x4 yreg[2][4];
#pragma unroll
  for (int t = 0; t < 2; ++t)
#pragma unroll
    for (int i = 0; i < 4; ++i)
      yreg[t][i] = *(const f32x4*)(out + (size_t)(bb + t * 16 + s) * 256 +
                                   wv * 64 + i * 16 + q * 4);

  // G0 = y0 @ W1^T (mm1 once)
  f32x4 G[2];
  G[0] = (f32x4){0.f, 0.f, 0.f, 0.f};
  G[1] = (f32x4){0.f, 0.f, 0.f, 0.f};
#pragma unroll
  for (int kt = 0; kt < 8; ++kt) {
    short8 w1f = pack8f(W1 + (size_t)(wv * 16 + s) * 256 + kt * 32 + q * 8);
#pragma unroll
    for (int t = 0; t < 2; ++t) {
      short8 yf = pack8f(out + (size_t)(bb + t * 16 + s) * 256 + kt * 32 + q * 8);
      G[t] = __builtin_amdgcn_mfma_f32_16x16x32_bf16(w1f, yf, G[t], 0, 0, 0);
    }
  }

  const int zwoff = (((wv * 2 + (q >> 1)) ^ sx7) << 4) + (q & 1) * 8;
  const int rb0 = s * 128, rb1 = (16 + s) * 128;

  auto stz = [&](char* buf, const f32x4 (&v)[2]) {
    *(u16x4*)(buf + rb0 + zwoff) = pack4(v[0]);
    *(u16x4*)(buf + rb1 + zwoff) = pack4(v[1]);
  };
  auto wcmm = [&](const char* buf, f32x4 (&o)[2]) {
#pragma unroll
    for (int t = 0; t < 2; ++t) {
      const char* rp = buf + (t ? rb1 : rb0);
      short8 zf0 = *(const short8*)(rp + ((q ^ sx7) << 4));
      short8 zf1 = *(const short8*)(rp + (((4 + q) ^ sx7) << 4));
      f32x4 a = (f32x4){0.f, 0.f, 0.f, 0.f};
      a = __builtin_amdgcn_mfma_f32_16x16x32_bf16(wcf[0], zf0, a, 0, 0, 0);
      a = __builtin_amdgcn_mfma_f32_16x16x32_bf16(wcf[1], zf1, a, 0, 0, 0);
      o[t] = a;
    }
  };
  // stage: exchange zc, then z_out = tanh(G + dt*(cj*u + zc@Wc^T) + b1)
  auto stage = [&](char* buf, const f32x4 (&zc)[2], float cj, f32x4 (&zo)[2]) {
    stz(buf, zc);
    __syncthreads();
    f32x4 o[2];
    wcmm(buf, o);
#pragma unroll
    for (int t = 0; t < 2; ++t)
#pragma unroll
      for (int r = 0; r < 4; ++r)
        zo[t][r] =
            fast_tanh(fmaf(dt[t], fmaf(cj, u4[r], o[t][r]), G[t][r]) + b1v[r]);
  };

  const float A31 = 3.f / 40.f, A32 = 9.f / 40.f;
  const float A41 = 44.f / 45.f, A42 = -56.f / 15.f, A43 = 32.f / 9.f;
  const float A51 = 19372.f / 6561.f, A52 = -25360.f / 2187.f,
              A53 = 64448.f / 6561.f, A54 = -212.f / 729.f;
  const float A61 = 9017.f / 3168.f, A62 = -355.f / 33.f, A63 = 46732.f / 5247.f,
              A64 = 49.f / 176.f, A65 = -5103.f / 18656.f;
  const float C1 = 35.f / 384.f, C3 = 500.f / 1113.f, C4 = 125.f / 192.f,
              C5 = -2187.f / 6784.f, C6 = 11.f / 84.f;

  f32x4 SC[2];
  SC[0] = (f32x4){0.f, 0.f, 0.f, 0.f};
  SC[1] = (f32x4){0.f, 0.f, 0.f, 0.f};
  f32x4 z1[2], z2[2], z3[2], z4[2], z5[2], z6[2], zc[2], o6[2];

  for (int st = 0; st < 8; ++st) {
    // z1 = tanh(G + b1): no exchange, no MFMA
#pragma unroll
    for (int t = 0; t < 2; ++t)
#pragma unroll
      for (int r = 0; r < 4; ++r) z1[t][r] = fast_tanh(G[t][r] + b1v[r]);

#pragma unroll
    for (int t = 0; t < 2; ++t) zc[t] = 0.2f * z1[t];
    stage(zA, zc, 0.2f, z2);
#pragma unroll
    for (int t = 0; t < 2; ++t) zc[t] = A31 * z1[t] + A32 * z2[t];
    stage(zB, zc, 0.3f, z3);
#pragma unroll
    for (int t = 0; t < 2; ++t) zc[t] = A41 * z1[t] + A42 * z2[t] + A43 * z3[t];
    stage(zA, zc, 0.8f, z4);
#pragma unroll
    for (int t = 0; t < 2; ++t)
      zc[t] = A51 * z1[t] + A52 * z2[t] + A53 * z3[t] + A54 * z4[t];
    stage(zB, zc, 8.f / 9.f, z5);
#pragma unroll
    for (int t = 0; t < 2; ++t)
      zc[t] = A61 * z1[t] + A62 * z2[t] + A63 * z3[t] + A64 * z4[t] + A65 * z5[t];
    stage(zA, zc, 1.0f, z6);

    // zC (output combo): G += dt*(u + zC@Wc^T); SC += zC
#pragma unroll
    for (int t = 0; t < 2; ++t)
      zc[t] = C1 * z1[t] + C3 * z3[t] + C4 * z4[t] + C5 * z5[t] + C6 * z6[t];
    stz(zB, zc);
    __syncthreads();
    wcmm(zB, o6);
#pragma unroll
    for (int t = 0; t < 2; ++t) {
      SC[t] += zc[t];
#pragma unroll
      for (int r = 0; r < 4; ++r)
        G[t][r] = fmaf(dt[t], u4[r] + o6[t][r], G[t][r]);
    }
  }

  // epilogue: y = y0 + dt*(8*b2 + SC@W2^T)   (mm2 once)
  stz(zA, SC);
  __syncthreads();
  short8 w2f[4][2];
#pragma unroll
  for (int i = 0; i < 4; ++i)
#pragma unroll
    for (int kt = 0; kt < 2; ++kt)
      w2f[i][kt] = pack8f(W2 + (size_t)(wv * 64 + i * 16 + s) * 64 + kt * 32 + q * 8);
  f32x4 b2v[4];
#pragma unroll
  for (int i = 0; i < 4; ++i) b2v[i] = *(const f32x4*)(b2 + wv * 64 + i * 16 + q * 4);

#pragma unroll
  for (int t = 0; t < 2; ++t) {
    const char* rp = zA + (t ? rb1 : rb0);
    short8 zf0 = *(const short8*)(rp + ((q ^ sx7) << 4));
    short8 zf1 = *(const short8*)(rp + (((4 + q) ^ sx7) << 4));
#pragma unroll
    for (int i = 0; i < 4; ++i) {
      f32x4 a = (f32x4){0.f, 0.f, 0.f, 0.f};
      a = __builtin_amdgcn_mfma_f32_16x16x32_bf16(w2f[i][0], zf0, a, 0, 0, 0);
      a = __builtin_amdgcn_mfma_f32_16x16x32_bf16(w2f[i][1], zf1, a, 0, 0, 0);
#pragma unroll
      for (int r = 0; r < 4; ++r)
        yreg[t][i][r] = fmaf(dt[t], fmaf(8.f, b2v[i][r], a[r]), yreg[t][i][r]);
    }
  }

#pragma unroll
  for (int t = 0; t < 2; ++t)
#pragma unroll
    for (int i = 0; i < 4; ++i)
      *(f32x4*)(out + (size_t)(bb + t * 16 + s) * 256 + wv * 64 + i * 16 + q * 4) =
          yreg[t][i];
}

extern "C" void kernel_launch(void* const* d_in, const int* in_sizes, int n_in,
                              void* d_out, int out_size, void* d_ws, size_t ws_size,
                              hipStream_t stream) {
  const float* x   = (const float*)d_in[0];
  const float* hp  = (const float*)d_in[1];
  const float* cp  = (const float*)d_in[2];
  const float* ts  = (const float*)d_in[3];
  const float* Wih = (const float*)d_in[4];
  const float* Whh = (const float*)d_in[5];
  const float* bih = (const float*)d_in[6];
  const float* bhh = (const float*)d_in[7];
  const float* W1  = (const float*)d_in[8];
  const float* b1  = (const float*)d_in[9];
  const float* W2  = (const float*)d_in[10];
  const float* b2  = (const float*)d_in[11];
  float* out = (float*)d_out;

  unsigned short* wsB = (unsigned short*)d_ws;            // 1 MB
  unsigned short* wcB = wsB + 1024 * 512;                 // 8 KB (bf16 64x64)
  float* uF = (float*)((char*)d_ws + 1024 * 1024 + 8192); // 256 B

  prep_kernel<<<273, 256, 0, stream>>>(Wih, Whh, W1, W2, b2, wsB, wcB, uF);
  lstm_kernel<<<dim3(4, 256), 256, 0, stream>>>(x, hp, cp, wsB, bih, bhh, out);
  ode_kernel<<<512, 256, 0, stream>>>(out, ts, W1, wcB, uF, W2, b1, b2);
}

// Round 7
// 90.342 us; speedup vs baseline: 5.7542x; 1.0811x over previous
//
#include <hip/hip_runtime.h>
#include <hip/hip_bf16.h>

// ODELSTMCell: B=16384, I=256, H=256, OH=64, 8 fixed dopri5 steps.
// prep_kernel : wsB = [W_ih|W_hh] bf16 [1024][512]; Wc = W1@W2 (64x64 bf16);
//               u = b2@W1^T (64 f32).
// lstm_kernel : R2-exact geometry (measured ~30us): grid(128,4), M=128/block,
//               MFMA GEMM via global_load_lds staging, fused epilogue.
// ode_kernel  : G-space dopri5 (R6-verified algebra), 16 samples/block,
//               grid 1024 -> 4 blocks/CU, launch_bounds(256,4), ~90 VGPR.

#define B_N 16384
#define H_N 256

typedef __attribute__((ext_vector_type(8))) short short8;          // 8 x bf16
typedef __attribute__((ext_vector_type(4))) unsigned short u16x4;  // 4 x bf16
typedef __attribute__((ext_vector_type(4))) float f32x4;

__device__ __forceinline__ unsigned short f2bf_s(float x) {
  __hip_bfloat16 h = __float2bfloat16(x);
  return *reinterpret_cast<unsigned short*>(&h);
}

__device__ __forceinline__ short8 pack8f(const float* p) {
  const f32x4 a = *(const f32x4*)p;
  const f32x4 b = *(const f32x4*)(p + 4);
  short8 r;
  r[0] = (short)f2bf_s(a[0]); r[1] = (short)f2bf_s(a[1]);
  r[2] = (short)f2bf_s(a[2]); r[3] = (short)f2bf_s(a[3]);
  r[4] = (short)f2bf_s(b[0]); r[5] = (short)f2bf_s(b[1]);
  r[6] = (short)f2bf_s(b[2]); r[7] = (short)f2bf_s(b[3]);
  return r;
}

__device__ __forceinline__ u16x4 pack4(f32x4 v) {
  u16x4 r;
  r[0] = f2bf_s(v[0]); r[1] = f2bf_s(v[1]);
  r[2] = f2bf_s(v[2]); r[3] = f2bf_s(v[3]);
  return r;
}

__device__ __forceinline__ float fast_sigmoid(float x) {
  return __builtin_amdgcn_rcpf(1.f + __expf(-x));
}
__device__ __forceinline__ float fast_tanh(float x) {
  x = fminf(15.f, fmaxf(-15.f, x));
  float e = __expf(2.f * x);
  return 1.f - 2.f * __builtin_amdgcn_rcpf(e + 1.f);
}

__device__ __forceinline__ void gl_lds16(const void* g, void* l) {
  __builtin_amdgcn_global_load_lds(
      (const __attribute__((address_space(1))) void*)g,
      (__attribute__((address_space(3))) void*)l, 16, 0, 0);
}

// ---------------------------------------------------------------------------
// prep: blocks [0,256): wsB rows; [256,272): Wc = W1@W2; 272: u = b2@W1^T.
// ---------------------------------------------------------------------------
__global__ __launch_bounds__(256) void prep_kernel(
    const float* __restrict__ Wih, const float* __restrict__ Whh,
    const float* __restrict__ W1, const float* __restrict__ W2,
    const float* __restrict__ b2,
    unsigned short* __restrict__ wsB, unsigned short* __restrict__ wcB,
    float* __restrict__ uF) {
  const int bx = blockIdx.x;
  if (bx < 256) {
    int idx = bx * 256 + threadIdx.x;
    int n = idx >> 6, c = idx & 63, k = c * 8;
    const float* src = (k < 256) ? (Wih + (size_t)n * 256 + k)
                                 : (Whh + (size_t)n * 256 + (k - 256));
    *(short8*)(wsB + (size_t)n * 512 + k) = pack8f(src);
  } else if (bx < 272) {
    int idx = (bx - 256) * 256 + threadIdx.x;  // [0,4096)
    int f = idx >> 6, o = idx & 63;
    float acc = 0.f;
    for (int h = 0; h < 256; ++h)
      acc = fmaf(W1[f * 256 + h], W2[h * 64 + o], acc);
    wcB[f * 64 + o] = f2bf_s(acc);
  } else {
    int f = threadIdx.x;
    if (f < 64) {
      float acc = 0.f;
      for (int h = 0; h < 256; ++h) acc = fmaf(W1[f * 256 + h], b2[h], acc);
      uF[f] = acc;
    }
  }
}

// ---------------------------------------------------------------------------
// lstm (R2-exact): grid (128, 4), 256 thr. Block: 128 samples x 64 h-units.
// LDS: As f32 [128][64] (chunk-swizzled ^row&15), Bs bf16 [256][64] (^row&7).
// ---------------------------------------------------------------------------
__global__ __launch_bounds__(256, 2) void lstm_kernel(
    const float* __restrict__ x, const float* __restrict__ hp,
    const float* __restrict__ cp, const unsigned short* __restrict__ wsB,
    const float* __restrict__ bih, const float* __restrict__ bhh,
    float* __restrict__ out) {
  __shared__ __align__(16) float As[128 * 64];
  __shared__ __align__(16) unsigned short Bs[256 * 64];

  const int lane = threadIdx.x & 63;
  const int wv = threadIdx.x >> 6;
  const int s = lane & 15, q = lane >> 4;
  const int mb = blockIdx.x * 128;
  const int hb = blockIdx.y * 64;

  f32x4 acc[2][16];
#pragma unroll
  for (int mt = 0; mt < 2; ++mt)
#pragma unroll
    for (int tn = 0; tn < 16; ++tn) acc[mt][tn] = (f32x4){0.f, 0.f, 0.f, 0.f};

  float bsum[16];
#pragma unroll
  for (int tn = 0; tn < 16; ++tn) {
    int n = (tn >> 2) * 256 + hb + (tn & 3) * 16 + s;
    bsum[tn] = bih[n] + bhh[n];
  }

  for (int kt8 = 0; kt8 < 8; ++kt8) {
    const int k0 = kt8 * 64;
    if (kt8) __syncthreads();  // WAR: previous compute done
    {
      const float* srcA = (k0 < 256) ? x : hp;
      const int kl = k0 & 255;
#pragma unroll
      for (int c = 0; c < 8; ++c) {
        int row = (wv * 8 + c) * 4 + (lane >> 4);
        int uc = (lane & 15) ^ (row & 15);
        gl_lds16(srcA + (size_t)(mb + row) * 256 + kl + uc * 4,
                 (char*)As + (wv * 8 + c) * 1024);
      }
    }
#pragma unroll
    for (int c = 0; c < 8; ++c) {
      int t = (wv * 8 + c) * 8 + (lane >> 3);
      int uc = (lane & 7) ^ (t & 7);
      int gr = (t >> 6) * 256 + hb + (t & 63);
      gl_lds16(wsB + (size_t)gr * 512 + k0 + uc * 8,
               (char*)Bs + (wv * 8 + c) * 1024);
    }
    __syncthreads();

#pragma unroll
    for (int kk = 0; kk < 2; ++kk) {
      short8 af[2];
#pragma unroll
      for (int mt = 0; mt < 2; ++mt) {
        int ar = wv * 32 + mt * 16 + s;
        int c0 = kk * 8 + q * 2;
        float tmp[8];
        *(f32x4*)tmp = *(const f32x4*)((char*)As + ar * 256 + ((c0 ^ (ar & 15)) * 16));
        *(f32x4*)(tmp + 4) =
            *(const f32x4*)((char*)As + ar * 256 + (((c0 + 1) ^ (ar & 15)) * 16));
        af[mt] = pack8f(tmp);
      }
#pragma unroll
      for (int tn = 0; tn < 16; ++tn) {
        int t = (tn >> 2) * 64 + (tn & 3) * 16 + s;
        int ch = (kk * 4 + q) ^ (t & 7);
        short8 bf = *(const short8*)((char*)Bs + t * 128 + ch * 16);
        acc[0][tn] = __builtin_amdgcn_mfma_f32_16x16x32_bf16(af[0], bf, acc[0][tn], 0, 0, 0);
        acc[1][tn] = __builtin_amdgcn_mfma_f32_16x16x32_bf16(af[1], bf, acc[1][tn], 0, 0, 0);
      }
    }
  }

#pragma unroll
  for (int mt = 0; mt < 2; ++mt)
#pragma unroll
    for (int ntl = 0; ntl < 4; ++ntl)
#pragma unroll
      for (int r = 0; r < 4; ++r) {
        int sample = mb + wv * 32 + mt * 16 + q * 4 + r;
        int h = hb + ntl * 16 + s;
        float gi = acc[mt][ntl][r]      + bsum[ntl];
        float gf = acc[mt][4 + ntl][r]  + bsum[4 + ntl];
        float gg = acc[mt][8 + ntl][r]  + bsum[8 + ntl];
        float go = acc[mt][12 + ntl][r] + bsum[12 + ntl];
        float iv = fast_sigmoid(gi), fv = fast_sigmoid(gf);
        float gv = fast_tanh(gg), ov = fast_sigmoid(go);
        float c = fv * cp[(size_t)sample * 256 + h] + iv * gv;
        float hv = ov * fast_tanh(c);
        out[(size_t)B_N * H_N + (size_t)sample * 256 + h] = c;
        out[(size_t)sample * 256 + h] = hv;
      }
}

// ---------------------------------------------------------------------------
// ode: G-space dopri5 (R6 algebra), 16 samples/block, 256 thr, 4 waves.
// Thread (s,q,wv): G/z/SC hold z-features wv*16+q*4..+3 of sample s;
// yreg holds y-features wv*64+i*16+q*4..+3. Grid 1024 -> 4 blocks/CU.
// ---------------------------------------------------------------------------
__global__ __launch_bounds__(256, 4) void ode_kernel(
    float* __restrict__ out, const float* __restrict__ ts,
    const float* __restrict__ W1, const unsigned short* __restrict__ wcB,
    const float* __restrict__ uF, const float* __restrict__ W2,
    const float* __restrict__ b1, const float* __restrict__ b2) {
  __shared__ __align__(16) unsigned short zcA[16 * 64];
  __shared__ __align__(16) unsigned short zcB2[16 * 64];
  char* zA = (char*)zcA;
  char* zB = (char*)zcB2;

  const int tid = threadIdx.x;
  const int lane = tid & 63, wv = tid >> 6;
  const int s = lane & 15, q = lane >> 4;
  const int bb = blockIdx.x * 16;
  const int sx7 = s & 7;

  short8 wcf[2];
#pragma unroll
  for (int kt = 0; kt < 2; ++kt)
    wcf[kt] = *(const short8*)(wcB + (size_t)(wv * 16 + s) * 64 + kt * 32 + q * 8);

  const f32x4 b1v = *(const f32x4*)(b1 + wv * 16 + q * 4);
  const f32x4 u4 = *(const f32x4*)(uF + wv * 16 + q * 4);
  const float dt = ts[bb + s] * 0.125f;

  f32x4 yreg[4];
#pragma unroll
  for (int i = 0; i < 4; ++i)
    yreg[i] = *(const f32x4*)(out + (size_t)(bb + s) * 256 + wv * 64 + i * 16 + q * 4);

  // G0 = y0 @ W1^T (mm1 once)
  f32x4 G = (f32x4){0.f, 0.f, 0.f, 0.f};
#pragma unroll
  for (int kt = 0; kt < 8; ++kt) {
    short8 w1f = pack8f(W1 + (size_t)(wv * 16 + s) * 256 + kt * 32 + q * 8);
    short8 yf = pack8f(out + (size_t)(bb + s) * 256 + kt * 32 + q * 8);
    G = __builtin_amdgcn_mfma_f32_16x16x32_bf16(w1f, yf, G, 0, 0, 0);
  }

  const int zwoff = (((wv * 2 + (q >> 1)) ^ sx7) << 4) + (q & 1) * 8;
  const int rb = s * 128;

  auto stz = [&](char* buf, f32x4 v) { *(u16x4*)(buf + rb + zwoff) = pack4(v); };
  auto wcmm = [&](const char* buf) -> f32x4 {
    const char* rp = buf + rb;
    short8 zf0 = *(const short8*)(rp + ((q ^ sx7) << 4));
    short8 zf1 = *(const short8*)(rp + (((4 + q) ^ sx7) << 4));
    f32x4 a = (f32x4){0.f, 0.f, 0.f, 0.f};
    a = __builtin_amdgcn_mfma_f32_16x16x32_bf16(wcf[0], zf0, a, 0, 0, 0);
    a = __builtin_amdgcn_mfma_f32_16x16x32_bf16(wcf[1], zf1, a, 0, 0, 0);
    return a;
  };
  auto stage = [&](char* buf, f32x4 zc, float cj) -> f32x4 {
    stz(buf, zc);
    __syncthreads();
    f32x4 o = wcmm(buf);
    f32x4 zo;
#pragma unroll
    for (int r = 0; r < 4; ++r)
      zo[r] = fast_tanh(fmaf(dt, fmaf(cj, u4[r], o[r]), G[r]) + b1v[r]);
    return zo;
  };

  const float A31 = 3.f / 40.f, A32 = 9.f / 40.f;
  const float A41 = 44.f / 45.f, A42 = -56.f / 15.f, A43 = 32.f / 9.f;
  const float A51 = 19372.f / 6561.f, A52 = -25360.f / 2187.f,
              A53 = 64448.f / 6561.f, A54 = -212.f / 729.f;
  const float A61 = 9017.f / 3168.f, A62 = -355.f / 33.f, A63 = 46732.f / 5247.f,
              A64 = 49.f / 176.f, A65 = -5103.f / 18656.f;
  const float C1 = 35.f / 384.f, C3 = 500.f / 1113.f, C4 = 125.f / 192.f,
              C5 = -2187.f / 6784.f, C6 = 11.f / 84.f;

  f32x4 SC = (f32x4){0.f, 0.f, 0.f, 0.f};

  for (int st = 0; st < 8; ++st) {
    f32x4 z1;
#pragma unroll
    for (int r = 0; r < 4; ++r) z1[r] = fast_tanh(G[r] + b1v[r]);

    f32x4 z2 = stage(zA, 0.2f * z1, 0.2f);
    f32x4 z3 = stage(zB, A31 * z1 + A32 * z2, 0.3f);
    f32x4 z4 = stage(zA, A41 * z1 + A42 * z2 + A43 * z3, 0.8f);
    f32x4 z5 = stage(zB, A51 * z1 + A52 * z2 + A53 * z3 + A54 * z4, 8.f / 9.f);
    f32x4 z6 = stage(zA, A61 * z1 + A62 * z2 + A63 * z3 + A64 * z4 + A65 * z5, 1.0f);

    f32x4 zc = C1 * z1 + C3 * z3 + C4 * z4 + C5 * z5 + C6 * z6;
    stz(zB, zc);
    __syncthreads();
    f32x4 o6 = wcmm(zB);
    SC += zc;
#pragma unroll
    for (int r = 0; r < 4; ++r) G[r] = fmaf(dt, u4[r] + o6[r], G[r]);
  }

  // epilogue: y = y0 + dt*(8*b2 + SC@W2^T)   (mm2 once)
  stz(zA, SC);
  __syncthreads();
  {
    const char* rp = zA + rb;
    short8 zf0 = *(const short8*)(rp + ((q ^ sx7) << 4));
    short8 zf1 = *(const short8*)(rp + (((4 + q) ^ sx7) << 4));
#pragma unroll
    for (int i = 0; i < 4; ++i) {
      short8 w2f0 = pack8f(W2 + (size_t)(wv * 64 + i * 16 + s) * 64 + q * 8);
      short8 w2f1 = pack8f(W2 + (size_t)(wv * 64 + i * 16 + s) * 64 + 32 + q * 8);
      f32x4 a = (f32x4){0.f, 0.f, 0.f, 0.f};
      a = __builtin_amdgcn_mfma_f32_16x16x32_bf16(w2f0, zf0, a, 0, 0, 0);
      a = __builtin_amdgcn_mfma_f32_16x16x32_bf16(w2f1, zf1, a, 0, 0, 0);
      f32x4 b2v = *(const f32x4*)(b2 + wv * 64 + i * 16 + q * 4);
#pragma unroll
      for (int r = 0; r < 4; ++r)
        yreg[i][r] = fmaf(dt, fmaf(8.f, b2v[r], a[r]), yreg[i][r]);
    }
  }

#pragma unroll
  for (int i = 0; i < 4; ++i)
    *(f32x4*)(out + (size_t)(bb + s) * 256 + wv * 64 + i * 16 + q * 4) = yreg[i];
}

extern "C" void kernel_launch(void* const* d_in, const int* in_sizes, int n_in,
                              void* d_out, int out_size, void* d_ws, size_t ws_size,
                              hipStream_t stream) {
  const float* x   = (const float*)d_in[0];
  const float* hp  = (const float*)d_in[1];
  const float* cp  = (const float*)d_in[2];
  const float* ts  = (const float*)d_in[3];
  const float* Wih = (const float*)d_in[4];
  const float* Whh = (const float*)d_in[5];
  const float* bih = (const float*)d_in[6];
  const float* bhh = (const float*)d_in[7];
  const float* W1  = (const float*)d_in[8];
  const float* b1  = (const float*)d_in[9];
  const float* W2  = (const float*)d_in[10];
  const float* b2  = (const float*)d_in[11];
  float* out = (float*)d_out;

  unsigned short* wsB = (unsigned short*)d_ws;            // 1 MB
  unsigned short* wcB = wsB + 1024 * 512;                 // 8 KB (bf16 64x64)
  float* uF = (float*)((char*)d_ws + 1024 * 1024 + 8192); // 256 B

  prep_kernel<<<273, 256, 0, stream>>>(Wih, Whh, W1, W2, b2, wsB, wcB, uF);
  lstm_kernel<<<dim3(128, 4), 256, 0, stream>>>(x, hp, cp, wsB, bih, bhh, out);
  ode_kernel<<<1024, 256, 0, stream>>>(out, ts, W1, wcB, uF, W2, b1, b2);
}

// Round 8
// 79.046 us; speedup vs baseline: 6.5765x; 1.1429x over previous
//
#include <hip/hip_runtime.h>
#include <hip/hip_bf16.h>

// ODELSTMCell: B=16384, I=256, H=256, OH=64, 8 fixed dopri5 steps.
// prep_kernel : wsB = [W_ih|W_hh] bf16 [1024][512]; Wc = W1@W2 (64x64 bf16);
//               u = b2@W1^T (64 f32).
// lstm_kernel : 512-thr, 2D wave split (4 row x 2 col), K=32 double-buffered
//               LDS with prefetch-before-compute (T3-lite 2-phase), 16 waves/CU.
// ode_kernel  : G-space dopri5 (R6/R7-verified), 16 samples/block, grid 1024.

#define B_N 16384
#define H_N 256

typedef __attribute__((ext_vector_type(8))) short short8;          // 8 x bf16
typedef __attribute__((ext_vector_type(4))) unsigned short u16x4;  // 4 x bf16
typedef __attribute__((ext_vector_type(4))) float f32x4;

__device__ __forceinline__ unsigned short f2bf_s(float x) {
  __hip_bfloat16 h = __float2bfloat16(x);
  return *reinterpret_cast<unsigned short*>(&h);
}

__device__ __forceinline__ short8 pack8f(const float* p) {
  const f32x4 a = *(const f32x4*)p;
  const f32x4 b = *(const f32x4*)(p + 4);
  short8 r;
  r[0] = (short)f2bf_s(a[0]); r[1] = (short)f2bf_s(a[1]);
  r[2] = (short)f2bf_s(a[2]); r[3] = (short)f2bf_s(a[3]);
  r[4] = (short)f2bf_s(b[0]); r[5] = (short)f2bf_s(b[1]);
  r[6] = (short)f2bf_s(b[2]); r[7] = (short)f2bf_s(b[3]);
  return r;
}

__device__ __forceinline__ u16x4 pack4(f32x4 v) {
  u16x4 r;
  r[0] = f2bf_s(v[0]); r[1] = f2bf_s(v[1]);
  r[2] = f2bf_s(v[2]); r[3] = f2bf_s(v[3]);
  return r;
}

__device__ __forceinline__ float fast_sigmoid(float x) {
  return __builtin_amdgcn_rcpf(1.f + __expf(-x));
}
__device__ __forceinline__ float fast_tanh(float x) {
  x = fminf(15.f, fmaxf(-15.f, x));
  float e = __expf(2.f * x);
  return 1.f - 2.f * __builtin_amdgcn_rcpf(e + 1.f);
}

__device__ __forceinline__ void gl_lds16(const void* g, void* l) {
  __builtin_amdgcn_global_load_lds(
      (const __attribute__((address_space(1))) void*)g,
      (__attribute__((address_space(3))) void*)l, 16, 0, 0);
}

// ---------------------------------------------------------------------------
// prep: blocks [0,256): wsB rows; [256,272): Wc = W1@W2; 272: u = b2@W1^T.
// ---------------------------------------------------------------------------
__global__ __launch_bounds__(256) void prep_kernel(
    const float* __restrict__ Wih, const float* __restrict__ Whh,
    const float* __restrict__ W1, const float* __restrict__ W2,
    const float* __restrict__ b2,
    unsigned short* __restrict__ wsB, unsigned short* __restrict__ wcB,
    float* __restrict__ uF) {
  const int bx = blockIdx.x;
  if (bx < 256) {
    int idx = bx * 256 + threadIdx.x;
    int n = idx >> 6, c = idx & 63, k = c * 8;
    const float* src = (k < 256) ? (Wih + (size_t)n * 256 + k)
                                 : (Whh + (size_t)n * 256 + (k - 256));
    *(short8*)(wsB + (size_t)n * 512 + k) = pack8f(src);
  } else if (bx < 272) {
    int idx = (bx - 256) * 256 + threadIdx.x;  // [0,4096)
    int f = idx >> 6, o = idx & 63;
    float a0 = 0.f, a1 = 0.f, a2 = 0.f, a3 = 0.f;
    for (int h = 0; h < 256; h += 4) {
      a0 = fmaf(W1[f * 256 + h],     W2[h * 64 + o],        a0);
      a1 = fmaf(W1[f * 256 + h + 1], W2[(h + 1) * 64 + o],  a1);
      a2 = fmaf(W1[f * 256 + h + 2], W2[(h + 2) * 64 + o],  a2);
      a3 = fmaf(W1[f * 256 + h + 3], W2[(h + 3) * 64 + o],  a3);
    }
    wcB[f * 64 + o] = f2bf_s((a0 + a1) + (a2 + a3));
  } else {
    int f = threadIdx.x;
    if (f < 64) {
      float a0 = 0.f, a1 = 0.f, a2 = 0.f, a3 = 0.f;
      for (int h = 0; h < 256; h += 4) {
        a0 = fmaf(W1[f * 256 + h],     b2[h],     a0);
        a1 = fmaf(W1[f * 256 + h + 1], b2[h + 1], a1);
        a2 = fmaf(W1[f * 256 + h + 2], b2[h + 2], a2);
        a3 = fmaf(W1[f * 256 + h + 3], b2[h + 3], a3);
      }
      uF[f] = (a0 + a1) + (a2 + a3);
    }
  }
}

// ---------------------------------------------------------------------------
// lstm: grid (128, 4), 512 thr (8 waves = 4 rowgrp x 2 colgrp).
// Block: 128 samples x 64 h-units. K=512 in 16 steps of 32, double-buffered.
// Wave (rg,cg): rows rg*32..+32 (2 mt), cols = 4 gates x [cg*32, cg*32+32).
// LDS/buffer: As [128][32] f32 (chunk^row&7), Bs [256][32] bf16 (chunk^(t>>1)&3).
// 2-phase: STAGE(next) -> compute(cur) -> barrier (drains prefetch).
// ---------------------------------------------------------------------------
__global__ __launch_bounds__(512, 4) void lstm_kernel(
    const float* __restrict__ x, const float* __restrict__ hp,
    const float* __restrict__ cp, const unsigned short* __restrict__ wsB,
    const float* __restrict__ bih, const float* __restrict__ bhh,
    float* __restrict__ out) {
  __shared__ __align__(16) float As2[2][128 * 32];           // 16KB x2
  __shared__ __align__(16) unsigned short Bs2[2][256 * 32];  // 16KB x2

  const int tid = threadIdx.x;
  const int lane = tid & 63;
  const int wv = tid >> 6;          // 0..7
  const int rg = wv >> 1;           // 0..3 (row group)
  const int cg = wv & 1;            // 0..1 (col group)
  const int s = lane & 15, q = lane >> 4;
  const int mb = blockIdx.x * 128;
  const int hb = blockIdx.y * 64;

  f32x4 acc[2][8];  // [mt][gate*2 + ntl]
#pragma unroll
  for (int mt = 0; mt < 2; ++mt)
#pragma unroll
    for (int tn = 0; tn < 8; ++tn) acc[mt][tn] = (f32x4){0.f, 0.f, 0.f, 0.f};

  // staging roles (per buffer = 16 x 1KB wave-chunks; wave wv does 2)
  const int c16a = wv * 2;           // A chunks c16a, c16a+1
  const int rowA0 = c16a * 8 + (lane >> 3);       // for chunk c16a
  const int gcA = (lane & 7) ^ (rowA0 & 7);       // row&7 == lane>>3 (both chunks)
  const int rowB0 = c16a * 16 + (lane >> 2);
  const int rowB1 = rowB0 + 16;
  const int gcB0 = (lane & 3) ^ ((rowB0 >> 1) & 3);
  const int gcB1 = (lane & 3) ^ ((rowB1 >> 1) & 3);
  const int grB0 = (rowB0 >> 6) * 256 + hb + (rowB0 & 63);
  const int grB1 = (rowB1 >> 6) * 256 + hb + (rowB1 & 63);

  auto STAGE = [&](int buf, int kt) {
    const float* srcA = (kt < 8) ? x : hp;
    const int kl = (kt * 32) & 255;
    gl_lds16(srcA + (size_t)(mb + rowA0) * 256 + kl + gcA * 4,
             (char*)As2[buf] + c16a * 1024);
    gl_lds16(srcA + (size_t)(mb + rowA0 + 8) * 256 + kl + gcA * 4,
             (char*)As2[buf] + (c16a + 1) * 1024);
    gl_lds16(wsB + (size_t)grB0 * 512 + kt * 32 + gcB0 * 8,
             (char*)Bs2[buf] + c16a * 1024);
    gl_lds16(wsB + (size_t)grB1 * 512 + kt * 32 + gcB1 * 8,
             (char*)Bs2[buf] + (c16a + 1) * 1024);
  };

  STAGE(0, 0);
  __syncthreads();

  for (int kt = 0; kt < 16; ++kt) {
    const int buf = kt & 1;
    if (kt < 15) STAGE(buf ^ 1, kt + 1);

    // A-frags: rows rg*32 + mt*16 + s, k = q*8..q*8+7 (f32 chunks 2q,2q+1)
    short8 af[2];
#pragma unroll
    for (int mt = 0; mt < 2; ++mt) {
      const int ar = rg * 32 + mt * 16 + s;
      const char* ap = (const char*)As2[buf] + ar * 128;
      float tmp[8];
      *(f32x4*)tmp = *(const f32x4*)(ap + (((q * 2) ^ (ar & 7)) << 4));
      *(f32x4*)(tmp + 4) = *(const f32x4*)(ap + (((q * 2 + 1) ^ (ar & 7)) << 4));
      af[mt] = pack8f(tmp);
    }
    const char* bp = (const char*)Bs2[buf];
#pragma unroll
    for (int tn = 0; tn < 8; ++tn) {
      const int t = (tn >> 1) * 64 + cg * 32 + (tn & 1) * 16 + s;
      short8 bfr = *(const short8*)(bp + t * 64 + ((q ^ ((t >> 1) & 3)) << 4));
      acc[0][tn] = __builtin_amdgcn_mfma_f32_16x16x32_bf16(af[0], bfr, acc[0][tn], 0, 0, 0);
      acc[1][tn] = __builtin_amdgcn_mfma_f32_16x16x32_bf16(af[1], bfr, acc[1][tn], 0, 0, 0);
    }
    __syncthreads();
  }

  // fused epilogue (bias loaded here to keep loop VGPRs low)
#pragma unroll
  for (int mt = 0; mt < 2; ++mt)
#pragma unroll
    for (int ntl = 0; ntl < 2; ++ntl)
#pragma unroll
      for (int r = 0; r < 4; ++r) {
        int sample = mb + rg * 32 + mt * 16 + q * 4 + r;
        int h = hb + cg * 32 + ntl * 16 + s;
        float gi = acc[mt][0 + ntl][r] + bih[h] + bhh[h];
        float gf = acc[mt][2 + ntl][r] + bih[256 + h] + bhh[256 + h];
        float gg = acc[mt][4 + ntl][r] + bih[512 + h] + bhh[512 + h];
        float go = acc[mt][6 + ntl][r] + bih[768 + h] + bhh[768 + h];
        float iv = fast_sigmoid(gi), fv = fast_sigmoid(gf);
        float gv = fast_tanh(gg), ov = fast_sigmoid(go);
        float c = fv * cp[(size_t)sample * 256 + h] + iv * gv;
        float hv = ov * fast_tanh(c);
        out[(size_t)B_N * H_N + (size_t)sample * 256 + h] = c;
        out[(size_t)sample * 256 + h] = hv;
      }
}

// ---------------------------------------------------------------------------
// ode: G-space dopri5 (verified), 16 samples/block, 256 thr, 4 waves.
// ---------------------------------------------------------------------------
__global__ __launch_bounds__(256, 4) void ode_kernel(
    float* __restrict__ out, const float* __restrict__ ts,
    const float* __restrict__ W1, const unsigned short* __restrict__ wcB,
    const float* __restrict__ uF, const float* __restrict__ W2,
    const float* __restrict__ b1, const float* __restrict__ b2) {
  __shared__ __align__(16) unsigned short zcA[16 * 64];
  __shared__ __align__(16) unsigned short zcB2[16 * 64];
  char* zA = (char*)zcA;
  char* zB = (char*)zcB2;

  const int tid = threadIdx.x;
  const int lane = tid & 63, wv = tid >> 6;
  const int s = lane & 15, q = lane >> 4;
  const int bb = blockIdx.x * 16;
  const int sx7 = s & 7;

  short8 wcf[2];
#pragma unroll
  for (int kt = 0; kt < 2; ++kt)
    wcf[kt] = *(const short8*)(wcB + (size_t)(wv * 16 + s) * 64 + kt * 32 + q * 8);

  const f32x4 b1v = *(const f32x4*)(b1 + wv * 16 + q * 4);
  const f32x4 u4 = *(const f32x4*)(uF + wv * 16 + q * 4);
  const float dt = ts[bb + s] * 0.125f;

  f32x4 yreg[4];
#pragma unroll
  for (int i = 0; i < 4; ++i)
    yreg[i] = *(const f32x4*)(out + (size_t)(bb + s) * 256 + wv * 64 + i * 16 + q * 4);

  // G0 = y0 @ W1^T (mm1 once)
  f32x4 G = (f32x4){0.f, 0.f, 0.f, 0.f};
#pragma unroll
  for (int kt = 0; kt < 8; ++kt) {
    short8 w1f = pack8f(W1 + (size_t)(wv * 16 + s) * 256 + kt * 32 + q * 8);
    short8 yf = pack8f(out + (size_t)(bb + s) * 256 + kt * 32 + q * 8);
    G = __builtin_amdgcn_mfma_f32_16x16x32_bf16(w1f, yf, G, 0, 0, 0);
  }

  const int zwoff = (((wv * 2 + (q >> 1)) ^ sx7) << 4) + (q & 1) * 8;
  const int rb = s * 128;

  auto stz = [&](char* buf, f32x4 v) { *(u16x4*)(buf + rb + zwoff) = pack4(v); };
  auto wcmm = [&](const char* buf) -> f32x4 {
    const char* rp = buf + rb;
    short8 zf0 = *(const short8*)(rp + ((q ^ sx7) << 4));
    short8 zf1 = *(const short8*)(rp + (((4 + q) ^ sx7) << 4));
    f32x4 a = (f32x4){0.f, 0.f, 0.f, 0.f};
    a = __builtin_amdgcn_mfma_f32_16x16x32_bf16(wcf[0], zf0, a, 0, 0, 0);
    a = __builtin_amdgcn_mfma_f32_16x16x32_bf16(wcf[1], zf1, a, 0, 0, 0);
    return a;
  };
  auto stage = [&](char* buf, f32x4 zc, float cj) -> f32x4 {
    stz(buf, zc);
    __syncthreads();
    f32x4 o = wcmm(buf);
    f32x4 zo;
#pragma unroll
    for (int r = 0; r < 4; ++r)
      zo[r] = fast_tanh(fmaf(dt, fmaf(cj, u4[r], o[r]), G[r]) + b1v[r]);
    return zo;
  };

  const float A31 = 3.f / 40.f, A32 = 9.f / 40.f;
  const float A41 = 44.f / 45.f, A42 = -56.f / 15.f, A43 = 32.f / 9.f;
  const float A51 = 19372.f / 6561.f, A52 = -25360.f / 2187.f,
              A53 = 64448.f / 6561.f, A54 = -212.f / 729.f;
  const float A61 = 9017.f / 3168.f, A62 = -355.f / 33.f, A63 = 46732.f / 5247.f,
              A64 = 49.f / 176.f, A65 = -5103.f / 18656.f;
  const float C1 = 35.f / 384.f, C3 = 500.f / 1113.f, C4 = 125.f / 192.f,
              C5 = -2187.f / 6784.f, C6 = 11.f / 84.f;

  f32x4 SC = (f32x4){0.f, 0.f, 0.f, 0.f};

  for (int st = 0; st < 8; ++st) {
    f32x4 z1;
#pragma unroll
    for (int r = 0; r < 4; ++r) z1[r] = fast_tanh(G[r] + b1v[r]);

    f32x4 z2 = stage(zA, 0.2f * z1, 0.2f);
    f32x4 z3 = stage(zB, A31 * z1 + A32 * z2, 0.3f);
    f32x4 z4 = stage(zA, A41 * z1 + A42 * z2 + A43 * z3, 0.8f);
    f32x4 z5 = stage(zB, A51 * z1 + A52 * z2 + A53 * z3 + A54 * z4, 8.f / 9.f);
    f32x4 z6 = stage(zA, A61 * z1 + A62 * z2 + A63 * z3 + A64 * z4 + A65 * z5, 1.0f);

    f32x4 zc = C1 * z1 + C3 * z3 + C4 * z4 + C5 * z5 + C6 * z6;
    stz(zB, zc);
    __syncthreads();
    f32x4 o6 = wcmm(zB);
    SC += zc;
#pragma unroll
    for (int r = 0; r < 4; ++r) G[r] = fmaf(dt, u4[r] + o6[r], G[r]);
  }

  // epilogue: y = y0 + dt*(8*b2 + SC@W2^T)   (mm2 once)
  stz(zA, SC);
  __syncthreads();
  {
    const char* rp = zA + rb;
    short8 zf0 = *(const short8*)(rp + ((q ^ sx7) << 4));
    short8 zf1 = *(const short8*)(rp + (((4 + q) ^ sx7) << 4));
#pragma unroll
    for (int i = 0; i < 4; ++i) {
      short8 w2f0 = pack8f(W2 + (size_t)(wv * 64 + i * 16 + s) * 64 + q * 8);
      short8 w2f1 = pack8f(W2 + (size_t)(wv * 64 + i * 16 + s) * 64 + 32 + q * 8);
      f32x4 a = (f32x4){0.f, 0.f, 0.f, 0.f};
      a = __builtin_amdgcn_mfma_f32_16x16x32_bf16(w2f0, zf0, a, 0, 0, 0);
      a = __builtin_amdgcn_mfma_f32_16x16x32_bf16(w2f1, zf1, a, 0, 0, 0);
      f32x4 b2v = *(const f32x4*)(b2 + wv * 64 + i * 16 + q * 4);
#pragma unroll
      for (int r = 0; r < 4; ++r)
        yreg[i][r] = fmaf(dt, fmaf(8.f, b2v[r], a[r]), yreg[i][r]);
    }
  }

#pragma unroll
  for (int i = 0; i < 4; ++i)
    *(f32x4*)(out + (size_t)(bb + s) * 256 + wv * 64 + i * 16 + q * 4) = yreg[i];
}

extern "C" void kernel_launch(void* const* d_in, const int* in_sizes, int n_in,
                              void* d_out, int out_size, void* d_ws, size_t ws_size,
                              hipStream_t stream) {
  const float* x   = (const float*)d_in[0];
  const float* hp  = (const float*)d_in[1];
  const float* cp  = (const float*)d_in[2];
  const float* ts  = (const float*)d_in[3];
  const float* Wih = (const float*)d_in[4];
  const float* Whh = (const float*)d_in[5];
  const float* bih = (const float*)d_in[6];
  const float* bhh = (const float*)d_in[7];
  const float* W1  = (const float*)d_in[8];
  const float* b1  = (const float*)d_in[9];
  const float* W2  = (const float*)d_in[10];
  const float* b2  = (const float*)d_in[11];
  float* out = (float*)d_out;

  unsigned short* wsB = (unsigned short*)d_ws;            // 1 MB
  unsigned short* wcB = wsB + 1024 * 512;                 // 8 KB (bf16 64x64)
  float* uF = (float*)((char*)d_ws + 1024 * 1024 + 8192); // 256 B

  prep_kernel<<<273, 256, 0, stream>>>(Wih, Whh, W1, W2, b2, wsB, wcB, uF);
  lstm_kernel<<<dim3(128, 4), 512, 0, stream>>>(x, hp, cp, wsB, bih, bhh, out);
  ode_kernel<<<1024, 256, 0, stream>>>(out, ts, W1, wcB, uF, W2, b1, b2);
}